// Round 1
// baseline (377.923 us; speedup 1.0000x reference)
//
#include <hip/hip_runtime.h>
#include <hip/hip_bf16.h>

// LSTMCell fused kernel: ifgo = [x0 h0 x1 h1] @ W_blocks  (M=1024, N=8192, K=4096)
// + gate activations + c/h update, all in one kernel (no workspace).
// GEMM: bf16 MFMA 16x16x32, 128x128 block tile, BK=64, 256 threads (4 waves 2x2).
// Block columns are gate-interleaved (c_il = 4*u + gate) so the epilogue can do
// the i/f/g/o combine with 4 intra-quad __shfl's.

typedef short bf16x8 __attribute__((ext_vector_type(8)));   // 8 bf16 (4 VGPRs)
typedef float f32x4  __attribute__((ext_vector_type(4)));

#define LDK 72   // padded K-stride (bf16 elems): 64 + 8 keeps ds_*_b128 uniform across banks

__device__ __forceinline__ short to_bf16(float f) {
  union { float f; unsigned u; } v; v.f = f;
  unsigned r = v.u + 0x7fffu + ((v.u >> 16) & 1u);   // RNE
  return (short)(r >> 16);
}

__global__ __launch_bounds__(256, 2)
void lstm_fused(const float* __restrict__ x, const float* __restrict__ h,
                const float* __restrict__ cin, const float* __restrict__ W,
                float* __restrict__ out)
{
  __shared__ short As[128 * LDK];   // A[m][k], k-contiguous
  __shared__ short Bs[128 * LDK];   // B^T[c_il][k], k-contiguous

  const int tid  = threadIdx.x;
  const int lane = tid & 63;
  const int wid  = tid >> 6;
  const int wr   = wid >> 1;        // wave row half (0..1)
  const int wc   = wid & 1;         // wave col half (0..1)

  // Grid: 512 blocks = 8 row-blocks x 64 col-blocks. Decompose so the 8 row-siblings
  // that share a W tile have bid % 8 == colblk % 8 -> same XCD (L2 reuse of W).
  const int bid     = blockIdx.x;
  const int rowblk  = bid >> 6;          // 0..7
  const int colblk  = bid & 63;          // 0..63
  const int n       = colblk >> 5;       // n-split 0..1
  const int u0      = (colblk & 31) * 32;
  const int rowbase = rowblk * 128;

  // A staging: thread owns rows {ar, ar+64}, cols [ac, ac+16)
  const int ar = tid >> 2;
  const int ac = (tid & 3) * 16;
  // B staging: thread owns W column gcol, k-rows {khalf*32 + kk*8 + j}
  const int cgm  = tid & 127;            // gate-major col id
  const int bg   = cgm >> 5;             // gate 0..3
  const int buo  = cgm & 31;             // u offset in tile
  const int cil  = buo * 4 + bg;         // interleaved LDS col
  const int khalf = tid >> 7;
  const int gcol = bg * 1024 + u0 + buo; // column inside W[k][n] slab (4096 wide)

  const int am   = lane & 15;
  const int quad = lane >> 4;

  f32x4 acc[4][4];
  const f32x4 zero = {0.f, 0.f, 0.f, 0.f};
  #pragma unroll
  for (int i = 0; i < 4; ++i)
    #pragma unroll
    for (int j = 0; j < 4; ++j) acc[i][j] = zero;

  for (int kt = 0; kt < 64; ++kt) {
    // ---- global loads: A tile (x/h interleaved blocks of 1024 cols) ----
    const int blk = kt >> 4;                       // which 1024-wide j-block
    const float* asrc = (blk & 1) ? h : x;
    const int cb = (blk >> 1) * 1024 + (kt & 15) * 64;

    float av[2][16];
    #pragma unroll
    for (int rr = 0; rr < 2; ++rr) {
      const float4* p = (const float4*)(asrc + (rowbase + ar + rr * 64) * 2048 + cb + ac);
      #pragma unroll
      for (int q = 0; q < 4; ++q) {
        float4 v = p[q];
        av[rr][q * 4 + 0] = v.x; av[rr][q * 4 + 1] = v.y;
        av[rr][q * 4 + 2] = v.z; av[rr][q * 4 + 3] = v.w;
      }
    }

    // ---- global loads: B tile (W is [k][col]-major -> per-lane k-gather) ----
    const int kq = kt >> 5;                        // k-split 0..1
    const int d0 = (kt & 31) * 64;
    const int wrow0 = (kq * 2 + n) * 2048 + d0;
    float bv[4][8];
    #pragma unroll
    for (int kk = 0; kk < 4; ++kk) {
      const float* p = W + (wrow0 + khalf * 32 + kk * 8) * 4096 + gcol;
      #pragma unroll
      for (int j = 0; j < 8; ++j) bv[kk][j] = p[j * 4096];
    }

    // ---- convert to bf16 before the barrier (halves live registers) ----
    bf16x8 aw[2][2], bw[4];
    #pragma unroll
    for (int rr = 0; rr < 2; ++rr)
      #pragma unroll
      for (int hh = 0; hh < 2; ++hh)
        #pragma unroll
        for (int e = 0; e < 8; ++e)
          aw[rr][hh][e] = to_bf16(av[rr][hh * 8 + e]);
    #pragma unroll
    for (int kk = 0; kk < 4; ++kk)
      #pragma unroll
      for (int e = 0; e < 8; ++e)
        bw[kk][e] = to_bf16(bv[kk][e]);

    __syncthreads();   // previous iter's ds_reads complete before overwrite
    #pragma unroll
    for (int rr = 0; rr < 2; ++rr) {
      *(bf16x8*)&As[(ar + rr * 64) * LDK + ac]     = aw[rr][0];
      *(bf16x8*)&As[(ar + rr * 64) * LDK + ac + 8] = aw[rr][1];
    }
    #pragma unroll
    for (int kk = 0; kk < 4; ++kk)
      *(bf16x8*)&Bs[cil * LDK + khalf * 32 + kk * 8] = bw[kk];
    __syncthreads();

    // ---- MFMA phase: 2 k-steps of 32, 4x4 tiles of 16x16 per wave ----
    #pragma unroll
    for (int s = 0; s < 2; ++s) {
      bf16x8 af[4], bfr[4];
      #pragma unroll
      for (int tm = 0; tm < 4; ++tm)
        af[tm] = *(const bf16x8*)&As[(wr * 64 + tm * 16 + am) * LDK + s * 32 + quad * 8];
      #pragma unroll
      for (int tn = 0; tn < 4; ++tn)
        bfr[tn] = *(const bf16x8*)&Bs[(wc * 64 + tn * 16 + am) * LDK + s * 32 + quad * 8];
      #pragma unroll
      for (int tm = 0; tm < 4; ++tm)
        #pragma unroll
        for (int tn = 0; tn < 4; ++tn)
          acc[tm][tn] = __builtin_amdgcn_mfma_f32_16x16x32_bf16(
              af[tm], bfr[tn], acc[tm][tn], 0, 0, 0);
    }
  }

  // ---- fused LSTM epilogue ----
  // C/D layout: col = lane&15 (our c_il), row = quad*4 + reg. c_il = 4*u + gate,
  // so lanes {base..base+3} hold i,f,g,o pre-activations of one (row, u).
  const int BU   = 1024 * 2048;
  const int g    = lane & 3;
  const int base = lane & ~3;
  #pragma unroll
  for (int tn = 0; tn < 4; ++tn) {
    const int cil_ep = wc * 64 + tn * 16 + am;
    const int u   = u0 + (cil_ep >> 2);
    const int col = n * 1024 + u;
    #pragma unroll
    for (int tm = 0; tm < 4; ++tm) {
      const int brow0 = rowbase + wr * 64 + tm * 16 + quad * 4;
      #pragma unroll
      for (int r = 0; r < 4; ++r) {
        const int brow = brow0 + r;
        const float val = acc[tm][tn][r];
        // branchless: gate 2 -> tanh(val) = 2*sigmoid(2v)-1, else sigmoid(val)
        const float xs  = (g == 2) ? 2.f * val : val;
        const float sg  = 1.f / (1.f + __expf(-xs));
        const float act = (g == 2) ? (2.f * sg - 1.f) : sg;
        const float ig = __shfl(act, base + 0, 64);
        const float fg = __shfl(act, base + 1, 64);
        const float gg = __shfl(act, base + 2, 64);
        const float og = __shfl(act, base + 3, 64);
        const float cold = cin[brow * 2048 + col];
        const float nc = fg * cold + ig * gg;
        const float th = 1.f - 2.f / (1.f + __expf(2.f * nc));
        const float nh = og * th;
        if (g == 0) out[brow * 2048 + col]      = nh;   // new_h
        if (g == 1) out[BU + brow * 2048 + col] = nc;   // new_c
      }
    }
  }
}

extern "C" void kernel_launch(void* const* d_in, const int* in_sizes, int n_in,
                              void* d_out, int out_size, void* d_ws, size_t ws_size,
                              hipStream_t stream) {
  const float* x = (const float*)d_in[0];
  const float* h = (const float*)d_in[1];
  const float* c = (const float*)d_in[2];
  const float* W = (const float*)d_in[3];
  float* out = (float*)d_out;
  lstm_fused<<<dim3(512), dim3(256), 0, stream>>>(x, h, c, W, out);
}